// Round 1
// baseline (201.386 us; speedup 1.0000x reference)
//
#include <hip/hip_runtime.h>
#include <cstdint>

// FCOS post-processor, exact-semantics port of the JAX reference.
// N=32 images, C=1, H=100, W=168 -> 16800 locations; PRE_NMS=1000, POST=100.
//
// Pipeline:
//   K1 fcos_topk : per-image exact top-1000 (radix-select on unique 48-bit keys
//                  = sortable(sigmoid_f32) << 16 | (0xFFFF - idx), matching
//                  lax.top_k value-desc/index-asc order) + bitonic sort +
//                  box decode/clip/validity.
//   K2 fcos_mask : 1000x1024 pairwise IoU -> 64-bit suppression words (ballot).
//   K3 fcos_scan : sequential greedy-NMS scan (1 wave/image, register/shfl),
//                  then emit top-100 (kept ranks ascending, then zero-score
//                  fill ranks ascending == ref's top_k(kept_scores,100)).

typedef unsigned long long u64;
typedef unsigned int u32;

#define HW_TOT 16800
#define W_GRID 168
#define K_PRE  1000
#define NRANK  1024
#define N_IMG  32

// ws layout (bytes)
#define SCORES_OFF 0
#define VALID_OFF  (N_IMG * NRANK * 4)
#define BOXES_OFF  (VALID_OFF + N_IMG * NRANK * 4)
#define MASK_OFF   (BOXES_OFF + N_IMG * NRANK * 16)
#define WS_NEED    ((size_t)MASK_OFF + (size_t)N_IMG * NRANK * 16 * 8)

// ---------------------------------------------------------------- kernel 1
__global__ __launch_bounds__(1024) void fcos_topk(
    const float* __restrict__ box_cls, const float* __restrict__ box_reg,
    const int* __restrict__ imh, const int* __restrict__ imw,
    float* __restrict__ scores_ws, u32* __restrict__ valid_ws,
    float* __restrict__ boxes_ws)
{
  const int n = blockIdx.x;
  const int t = threadIdx.x;
  __shared__ u32 hist[256];
  __shared__ u64 prefix_s;
  __shared__ u32 kneed_s, cnt_s;
  __shared__ u64 skey[1024];

  // Build unique 48-bit keys. Sigmoid in f64 then rounded to f32 (best match
  // for ref rounding -> tie classes). Key low 16 bits: 0xFFFF - idx so that
  // descending key order == (score desc, index asc) == lax.top_k order.
  u64 kreg[17];
  const float* cls = box_cls + (size_t)n * HW_TOT;
  #pragma unroll
  for (int k = 0; k < 17; ++k) {
    int i = t + k * 1024;
    u64 key = 0;
    if (i < HW_TOT) {
      float x = cls[i];
      double sd = 1.0 / (1.0 + exp(-(double)x));
      float s = (float)sd;
      u32 b = __float_as_uint(s);
      u32 u = (b & 0x80000000u) ? ~b : (b | 0x80000000u);
      key = ((u64)u << 16) | (u64)(0xFFFFu - (u32)i);
    }
    kreg[k] = key;
  }
  if (t == 0) { prefix_s = 0ull; kneed_s = K_PRE; cnt_s = 0u; }
  __syncthreads();

  // 6-pass MSB radix select (8-bit digits over the 48-bit key).
  for (int p = 5; p >= 0; --p) {
    if (t < 256) hist[t] = 0u;
    __syncthreads();
    const u64 pref = prefix_s;
    const int sh = p * 8;
    #pragma unroll
    for (int k = 0; k < 17; ++k) {
      u64 key = kreg[k];
      if ((key >> (sh + 8)) == pref)
        atomicAdd(&hist[(u32)((key >> sh) & 0xFFull)], 1u);
    }
    __syncthreads();
    // inclusive suffix sum over 256 bins
    for (int off = 1; off < 256; off <<= 1) {
      u32 v = 0;
      if (t < 256) v = hist[t] + ((t + off < 256) ? hist[t + off] : 0u);
      __syncthreads();
      if (t < 256) hist[t] = v;
      __syncthreads();
    }
    bool sel = false; u32 kn = 0, gt = 0;
    if (t < 256) {
      u32 ge = hist[t];
      gt = (t < 255) ? hist[t + 1] : 0u;
      kn = kneed_s;
      sel = (ge >= kn) && (gt < kn);   // exactly one digit satisfies
    }
    const u64 curp = prefix_s;
    __syncthreads();
    if (sel) { prefix_s = (curp << 8) | (u64)t; kneed_s = kn - gt; }
    __syncthreads();
  }

  // Compact all keys >= T (keys unique -> exactly 1000), pad with 0.
  const u64 T = prefix_s;
  skey[t] = 0ull;
  __syncthreads();
  #pragma unroll
  for (int k = 0; k < 17; ++k) {
    if (kreg[k] >= T) {
      u32 pos = atomicAdd(&cnt_s, 1u);
      if (pos < 1024u) skey[pos] = kreg[k];
    }
  }
  __syncthreads();

  // Bitonic sort 1024 keys, descending (pads sink to ranks 1000..1023).
  for (u32 k2 = 2; k2 <= 1024; k2 <<= 1) {
    for (u32 j = k2 >> 1; j > 0; j >>= 1) {
      u32 partner = (u32)t ^ j;
      if (partner > (u32)t) {
        u64 a = skey[t], b = skey[partner];
        bool desc = (((u32)t & k2) == 0);
        if (desc ? (a < b) : (a > b)) { skey[t] = b; skey[partner] = a; }
      }
      __syncthreads();
    }
  }

  // Decode rank t.
  const float fw = (float)(*imw) - 1.0f;
  const float fh = (float)(*imh) - 1.0f;
  u64 key = skey[t];
  float* bx = boxes_ws + ((size_t)n * NRANK + t) * 4;
  if (t < K_PRE) {
    u32 u = (u32)(key >> 16);
    u32 b = (u & 0x80000000u) ? (u & 0x7FFFFFFFu) : ~u;
    float s = __uint_as_float(b);
    u32 idx = 0xFFFFu - (u32)(key & 0xFFFFull);
    int hh = (int)idx / W_GRID, ww = (int)idx - hh * W_GRID;
    float lx = (float)(ww * 8 + 4), ly = (float)(hh * 8 + 4);  // == locations
    const float* rg = box_reg + (size_t)n * 4 * HW_TOT + idx;
    float r0 = rg[0], r1 = rg[HW_TOT], r2 = rg[2 * HW_TOT], r3 = rg[3 * HW_TOT];
    float x1 = fminf(fmaxf(lx - r0, 0.0f), fw);
    float y1 = fminf(fmaxf(ly - r1, 0.0f), fh);
    float x2 = fminf(fmaxf(lx + r2, 0.0f), fw);
    float y2 = fminf(fmaxf(ly + r3, 0.0f), fh);
    bool valid = (s > 0.01f) && ((x2 - x1 + 1.0f) >= 0.0f)
                             && ((y2 - y1 + 1.0f) >= 0.0f);   // MIN_SIZE = 0
    scores_ws[n * NRANK + t] = s;
    valid_ws[n * NRANK + t] = valid ? 1u : 0u;
    bx[0] = x1; bx[1] = y1; bx[2] = x2; bx[3] = y2;
  } else {
    scores_ws[n * NRANK + t] = 0.0f;
    valid_ws[n * NRANK + t] = 0u;
    bx[0] = 0.0f; bx[1] = 0.0f; bx[2] = 0.0f; bx[3] = 0.0f;  // pad boxes: iou=0
  }
}

// ---------------------------------------------------------------- kernel 2
// Suppression mask: bit j of word c of row i  <=>  iou(box_i, box_{c*64+j}) > 0.5
// _rn intrinsics forbid FMA contraction so boundary bits match ref arithmetic.
__global__ __launch_bounds__(1024) void fcos_mask(
    const float* __restrict__ boxes_ws, u64* __restrict__ mask_ws)
{
  const int n = blockIdx.y, g = blockIdx.x;   // g: 8 row groups of 125
  const int t = threadIdx.x;
  __shared__ float4 bx[1024];
  bx[t] = ((const float4*)boxes_ws)[(size_t)n * NRANK + t];
  __syncthreads();
  const int wv = t >> 6, lane = t & 63;
  u64* mimg = mask_ws + (size_t)n * NRANK * 16;
  for (int r = wv; r < 125; r += 16) {
    const int i = g * 125 + r;
    const float4 bi = bx[i];
    const float ai = __fmul_rn(fmaxf(bi.z - bi.x, 0.0f), fmaxf(bi.w - bi.y, 0.0f));
    #pragma unroll
    for (int c = 0; c < 16; ++c) {
      const int j = c * 64 + lane;
      const float4 bj = bx[j];
      const float aj = __fmul_rn(fmaxf(bj.z - bj.x, 0.0f), fmaxf(bj.w - bj.y, 0.0f));
      float iw  = fmaxf(fminf(bi.z, bj.z) - fmaxf(bi.x, bj.x), 0.0f);
      float ih2 = fmaxf(fminf(bi.w, bj.w) - fmaxf(bi.y, bj.y), 0.0f);
      float inter = __fmul_rn(iw, ih2);
      float uni = fmaxf(__fsub_rn(__fadd_rn(ai, aj), inter), 1e-9f);
      float iou = inter / uni;                 // IEEE-correct f32 div (no fast-math)
      u64 m = __ballot(iou > 0.5f);
      if (lane == 0) mimg[(size_t)i * 16 + c] = m;
    }
  }
}

// ---------------------------------------------------------------- kernel 3
__global__ __launch_bounds__(64) void fcos_scan(
    const float* __restrict__ scores_ws, const u32* __restrict__ valid_ws,
    const float* __restrict__ boxes_ws, const u64* __restrict__ mask_ws,
    float* __restrict__ out)
{
  const int n = blockIdx.x;
  const int lane = threadIdx.x;
  const int l16 = lane & 15;
  const int q = lane >> 4;
  const u64* mbase = mask_ws + (size_t)n * NRANK * 16;

  // validity words; lane w (w<16) ends up owning word w
  u64 validw = 0;
  #pragma unroll
  for (int w = 0; w < 16; ++w) {
    u32 v = valid_ws[n * NRANK + w * 64 + lane];
    u64 b = __ballot(v != 0u);
    if (lane == w) validw = b;
  }

  u64 sup = 0, keepw = 0;
  u64 mA[16], mB[16];
  // chunk layout: lane (q,l16) holds word l16 of rows {chunk*64 + q*16 + r}
  #pragma unroll
  for (int r = 0; r < 16; ++r)
    mA[r] = mbase[(size_t)((q * 16 + r) * 16 + l16)];

  // Sequential greedy scan. cword = live copy of suppression word `blk`
  // (uniform across lanes); only alive rows do the shfl+OR work.
#define PROCESS(BLK, REGS) do {                                              \
    const int blk_ = (BLK);                                                  \
    const u64 iamblk = (lane == blk_) ? ~0ull : 0ull;                        \
    u64 vw = __shfl(validw, blk_);                                           \
    u64 cword = __shfl(sup, blk_);                                           \
    _Pragma("unroll")                                                        \
    for (int qq = 0; qq < 4; ++qq) {                                         \
      _Pragma("unroll")                                                      \
      for (int rr = 0; rr < 16; ++rr) {                                      \
        const int bit = qq * 16 + rr;                                        \
        u64 kp = ((vw >> bit) & 1ull) & (~(cword >> bit) & 1ull);            \
        if (kp) {                         /* uniform branch */               \
          u64 mrow = __shfl(REGS[rr], qq * 16 + l16);                        \
          u64 cupd = __shfl(REGS[rr], qq * 16 + blk_);                       \
          cword |= cupd;                                                     \
          sup   |= mrow;                                                     \
          keepw |= (1ull << bit) & iamblk;                                   \
        }                                                                    \
      }                                                                      \
    }                                                                        \
  } while (0)

  for (int bb = 0; bb < 16; bb += 2) {
    #pragma unroll
    for (int r = 0; r < 16; ++r)   // prefetch chunk bb+1
      mB[r] = mbase[(size_t)(((bb + 1) * 64 + q * 16 + r) * 16 + l16)];
    PROCESS(bb, mA);
    if (bb + 2 < 16) {
      #pragma unroll
      for (int r = 0; r < 16; ++r) // prefetch chunk bb+2
        mA[r] = mbase[(size_t)(((bb + 2) * 64 + q * 16 + r) * 16 + l16)];
    }
    PROCESS(bb + 1, mB);
  }
#undef PROCESS

  // Emit: slots 0..m-1 = kept ranks ascending; slots m..99 = non-kept ranks
  // ascending with score 0 (matches ref top_k(kept_scores,100) exactly).
  __shared__ u64 kw_s[16];
  __shared__ u32 cumk_s[17], cumn_s[17];
  if (lane < 16) kw_s[lane] = keepw;
  __syncthreads();
  if (lane == 0) {
    u32 ck = 0, cn = 0;
    for (int w = 0; w < 16; ++w) {
      cumk_s[w] = ck; cumn_s[w] = cn;
      u64 rm = (w == 15) ? ((1ull << 40) - 1ull) : ~0ull;  // ranks 960..999
      ck += (u32)__popcll(kw_s[w] & rm);
      cn += (u32)__popcll(~kw_s[w] & rm);
    }
    cumk_s[16] = ck; cumn_s[16] = cn;
  }
  __syncthreads();
  const u32 mtot = cumk_s[16];

  for (int s = lane; s < 100; s += 64) {
    u32 r; float sc;
    if ((u32)s < mtot) {
      int w = 0;
      #pragma unroll
      for (int x = 1; x < 16; ++x) if (cumk_s[x] <= (u32)s) w = x;
      u64 rm = (w == 15) ? ((1ull << 40) - 1ull) : ~0ull;
      u64 word = kw_s[w] & rm;
      u32 b = (u32)s - cumk_s[w];
      for (u32 z = 0; z < b; ++z) word &= word - 1;   // b-th set bit
      r = (u32)(w * 64) + (u32)(__ffsll((long long)word) - 1);
      sc = scores_ws[n * NRANK + r];
    } else {
      u32 s2 = (u32)s - mtot;
      int w = 0;
      #pragma unroll
      for (int x = 1; x < 16; ++x) if (cumn_s[x] <= s2) w = x;
      u64 rm = (w == 15) ? ((1ull << 40) - 1ull) : ~0ull;
      u64 word = (~kw_s[w]) & rm;
      u32 b = s2 - cumn_s[w];
      for (u32 z = 0; z < b; ++z) word &= word - 1;
      r = (u32)(w * 64) + (u32)(__ffsll((long long)word) - 1);
      sc = 0.0f;
    }
    const float* bxp = boxes_ws + ((size_t)n * NRANK + r) * 4;
    float* o = out + ((size_t)n * 100 + s) * 6;
    o[0] = bxp[0]; o[1] = bxp[1]; o[2] = bxp[2]; o[3] = bxp[3];
    o[4] = sc; o[5] = 1.0f;   // label = idx % C + 1 = 1 (C=1)
  }
}

// ---------------------------------------------------------------- launch
extern "C" void kernel_launch(void* const* d_in, const int* in_sizes, int n_in,
                              void* d_out, int out_size, void* d_ws, size_t ws_size,
                              hipStream_t stream) {
  (void)in_sizes; (void)n_in; (void)out_size;
  if (ws_size < WS_NEED) return;  // fail loudly (out stays zero)

  const float* box_cls = (const float*)d_in[1];
  const float* box_reg = (const float*)d_in[2];
  const int* imh = (const int*)d_in[4];
  const int* imw = (const int*)d_in[5];

  char* ws = (char*)d_ws;
  float* scores_ws = (float*)(ws + SCORES_OFF);
  u32*   valid_ws  = (u32*)(ws + VALID_OFF);
  float* boxes_ws  = (float*)(ws + BOXES_OFF);
  u64*   mask_ws   = (u64*)(ws + MASK_OFF);
  float* out = (float*)d_out;

  fcos_topk<<<N_IMG, 1024, 0, stream>>>(box_cls, box_reg, imh, imw,
                                        scores_ws, valid_ws, boxes_ws);
  dim3 gB(8, N_IMG);
  fcos_mask<<<gB, 1024, 0, stream>>>(boxes_ws, mask_ws);
  fcos_scan<<<N_IMG, 64, 0, stream>>>(scores_ws, valid_ws, boxes_ws, mask_ws, out);
}